// Round 4
// baseline (584.669 us; speedup 1.0000x reference)
//
#include <hip/hip_runtime.h>
#include <hip/hip_bf16.h>
#include <stdint.h>

#define M_TOTAL 16384   // BATCH * SEQ
#define N_TOTAL 4096    // OUT_FEATURES
#define K_TOTAL 4096    // IN_FEATURES

#define BM 256
#define BN 256
#define BK 64
#define NT (K_TOTAL / BK)   // 64 K-steps

typedef __attribute__((ext_vector_type(4))) float f32x4;
typedef __attribute__((ext_vector_type(4))) int   i32x4;
typedef __attribute__((ext_vector_type(8))) short s16x8;
typedef __attribute__((ext_vector_type(4))) short s16x4;

__device__ __forceinline__ unsigned short f32_to_bf16_rne(float f) {
  union { float f; unsigned u; } c; c.f = f;
  unsigned r = (c.u + 0x7fffu + ((c.u >> 16) & 1u)) >> 16;
  return (unsigned short)r;
}

// x fp32 (M,K) -> bf16 (M,K)
__global__ void cvt_x_kernel(const float* __restrict__ x,
                             unsigned short* __restrict__ xb) {
  const int n4 = M_TOTAL * (K_TOTAL / 4);
  int idx = blockIdx.x * blockDim.x + threadIdx.x;
  int stride = gridDim.x * blockDim.x;
  const f32x4* xv = (const f32x4*)x;
  s16x4* ov = (s16x4*)xb;
  for (int i = idx; i < n4; i += stride) {
    f32x4 v = xv[i];
    s16x4 o;
#pragma unroll
    for (int j = 0; j < 4; ++j) o[j] = (short)f32_to_bf16_rne(v[j]);
    ov[i] = o;
  }
}

// packed int4 (one byte per int32 elem) -> bf16 integer values (N, K) row-major.
__global__ void dequant_w_kernel(const int* __restrict__ wq,
                                 unsigned short* __restrict__ wb) {
  const int n = (N_TOTAL * (K_TOTAL / 2)) / 4;
  int idx = blockIdx.x * blockDim.x + threadIdx.x;
  int stride = gridDim.x * blockDim.x;
  const i32x4* wv = (const i32x4*)wq;
  s16x8* ov = (s16x8*)wb;
  for (int i = idx; i < n; i += stride) {
    i32x4 w = wv[i];
    s16x8 o;
#pragma unroll
    for (int j = 0; j < 4; ++j) {
      int b = w[j];
      int lo = ((b & 0xF) ^ 8) - 8;
      int hi = (((b >> 4) & 0xF) ^ 8) - 8;
      union { float f; unsigned u; } cl, ch;
      cl.f = (float)lo; ch.f = (float)hi;
      o[2 * j]     = (short)(cl.u >> 16);
      o[2 * j + 1] = (short)(ch.u >> 16);
    }
    ov[i] = o;
  }
}

#define MFMA16(a, b, c) __builtin_amdgcn_mfma_f32_16x16x32_bf16((a), (b), (c), 0, 0, 0)

// 256x256 tile, BK=64, 8 waves (2x4), 4-phase-per-K-tile m201-style schedule:
// each phase = {ds_read subtile, stage 1 half-tile, barrier, lgkm(0), 16 MFMA,
// barrier}; vmcnt(2) gate once per tile. T2 swizzle; T1 XCD mapping; T5 setprio.
__global__ __launch_bounds__(512, 2) void gemm256_kernel(
    const unsigned short* __restrict__ A,   // M x K bf16
    const unsigned short* __restrict__ B,   // N x K bf16 (int values)
    const float* __restrict__ scales,
    const float* __restrict__ bias,
    float* __restrict__ C) {
  // [buf][A=0/B=1][256 rows][64 cols] bf16 = 128 KB total
  __shared__ unsigned short lds[2][2][BM * BK];

  const int t  = threadIdx.x;
  const int l  = t & 63;
  const int w  = t >> 6;        // wave 0..7
  const int wm = w >> 2;        // 0..1 (M half)
  const int wn = w & 3;         // 0..3 (N quarter)
  const int fr = l & 15;
  const int kg = l >> 4;        // 0..3
  const int sx = fr & 7;        // T2 swizzle XOR (row&7 == fr&7 for all frags)

  // T1/L2: each XCD (wg&7) owns an exclusive 8-tile A block, sweeps bn.
  const int wg = blockIdx.x;                        // nwg = 1024
  const int bm = (wg & 7) * 8 + ((wg >> 3) & 7);    // 0..63
  const int bn = wg >> 6;                           // 0..15

  // Staging: linear LDS dest (global_load_lds), pre-swizzled global source.
  // Thread t stores (row_in_64 = t>>3, slot = t&7); slot holds logical
  // (t&7) ^ ((t>>3)&7).
  const int rr   = t >> 3;                 // 0..63
  const int ssrc = (t & 7) ^ (rr & 7);
  const unsigned short* pa = A + (size_t)(bm * BM + rr) * K_TOTAL + ssrc * 8;
  const unsigned short* pb = B + (size_t)(bn * BN + rr) * K_TOTAL + ssrc * 8;

#define GLL(gp, lp) __builtin_amdgcn_global_load_lds( \
      (const __attribute__((address_space(1))) unsigned int*)(gp), \
      (__attribute__((address_space(3))) unsigned int*)(lp), 16, 0, 0)

  // Stage one half-tile (2 GLL): mat 0=A,1=B; half 0/1 = rows h*128..h*128+127.
  auto stage_half = [&](int buf, int mat, int half, int kt) {
    const unsigned short* g0 = (mat == 0 ? pa : pb);
#pragma unroll
    for (int c = 0; c < 2; ++c) {
      GLL(g0 + (size_t)(half * 128 + c * 64) * K_TOTAL + kt,
          &lds[buf][mat][half * 8192 + c * 4096 + t * 8]);
    }
  };

  f32x4 acc[8][4] = {};

  // Prologue: tile 0 fully staged into buf 0.
  stage_half(0, 0, 0, 0); stage_half(0, 0, 1, 0);
  stage_half(0, 1, 0, 0); stage_half(0, 1, 1, 0);

  for (int t0 = 0; t0 < NT; ++t0) {
    const int cur = t0 & 1, nxt = cur ^ 1;
    const int ktn = (t0 + 1) * BK;
    const bool hasNext = (t0 + 1 < NT);

    const unsigned short* Abp = &lds[cur][0][(wm * 128 + fr) * BK];
    const unsigned short* Bbp = &lds[cur][1][(wn * 64 + fr) * BK];
    const int so0 = (kg ^ sx) * 8;         // kh0 slot (swizzled)
    const int so1 = ((4 + kg) ^ sx) * 8;   // kh1 slot

    // ---------- phase 1: gate + A/B kh0 reads + MFMA (kh0, n0-1) ----------
    if (hasNext) {
      stage_half(nxt, 0, 0, ktn);                       // A half0 of t+1
      asm volatile("s_waitcnt vmcnt(2)" ::: "memory");  // tile t's 8 landed
    } else {
      asm volatile("s_waitcnt vmcnt(0)" ::: "memory");
    }
    __builtin_amdgcn_sched_barrier(0);
    __builtin_amdgcn_s_barrier();                       // buf[cur] ready (all waves)
    __builtin_amdgcn_sched_barrier(0);

    s16x8 a0[8], b0[4], a1[8], b1[4];
#pragma unroll
    for (int m = 0; m < 8; ++m) a0[m] = *(const s16x8*)&Abp[m * 16 * BK + so0];
    b0[0] = *(const s16x8*)&Bbp[0 * 16 * BK + so0];
    b0[1] = *(const s16x8*)&Bbp[1 * 16 * BK + so0];
    asm volatile("s_waitcnt lgkmcnt(0)" ::: "memory");
    __builtin_amdgcn_sched_barrier(0);
    __builtin_amdgcn_s_setprio(1);
#pragma unroll
    for (int m = 0; m < 8; ++m)
#pragma unroll
      for (int n = 0; n < 2; ++n)
        acc[m][n] = MFMA16(a0[m], b0[n], acc[m][n]);
    __builtin_amdgcn_s_setprio(0);
    __builtin_amdgcn_sched_barrier(0);
    __builtin_amdgcn_s_barrier();
    __builtin_amdgcn_sched_barrier(0);

    // ---------- phase 2: B kh0 n2-3 reads + MFMA (kh0, n2-3) ----------
    b0[2] = *(const s16x8*)&Bbp[2 * 16 * BK + so0];
    b0[3] = *(const s16x8*)&Bbp[3 * 16 * BK + so0];
    if (hasNext) stage_half(nxt, 0, 1, ktn);            // A half1 of t+1
    __builtin_amdgcn_sched_barrier(0);
    __builtin_amdgcn_s_barrier();
    asm volatile("s_waitcnt lgkmcnt(0)" ::: "memory");
    __builtin_amdgcn_sched_barrier(0);
    __builtin_amdgcn_s_setprio(1);
#pragma unroll
    for (int m = 0; m < 8; ++m)
#pragma unroll
      for (int n = 2; n < 4; ++n)
        acc[m][n] = MFMA16(a0[m], b0[n], acc[m][n]);
    __builtin_amdgcn_s_setprio(0);
    __builtin_amdgcn_sched_barrier(0);
    __builtin_amdgcn_s_barrier();
    __builtin_amdgcn_sched_barrier(0);

    // ---------- phase 3: A/B kh1 reads + MFMA (kh1, n0-1) ----------
#pragma unroll
    for (int m = 0; m < 8; ++m) a1[m] = *(const s16x8*)&Abp[m * 16 * BK + so1];
    b1[0] = *(const s16x8*)&Bbp[0 * 16 * BK + so1];
    b1[1] = *(const s16x8*)&Bbp[1 * 16 * BK + so1];
    if (hasNext) stage_half(nxt, 1, 0, ktn);            // B half0 of t+1
    __builtin_amdgcn_sched_barrier(0);
    __builtin_amdgcn_s_barrier();
    asm volatile("s_waitcnt lgkmcnt(0)" ::: "memory");
    __builtin_amdgcn_sched_barrier(0);
    __builtin_amdgcn_s_setprio(1);
#pragma unroll
    for (int m = 0; m < 8; ++m)
#pragma unroll
      for (int n = 0; n < 2; ++n)
        acc[m][n] = MFMA16(a1[m], b1[n], acc[m][n]);
    __builtin_amdgcn_s_setprio(0);
    __builtin_amdgcn_sched_barrier(0);
    __builtin_amdgcn_s_barrier();
    __builtin_amdgcn_sched_barrier(0);

    // ---------- phase 4: B kh1 n2-3 reads + MFMA (kh1, n2-3) ----------
    b1[2] = *(const s16x8*)&Bbp[2 * 16 * BK + so1];
    b1[3] = *(const s16x8*)&Bbp[3 * 16 * BK + so1];
    if (hasNext) stage_half(nxt, 1, 1, ktn);            // B half1 of t+1
    __builtin_amdgcn_sched_barrier(0);
    __builtin_amdgcn_s_barrier();
    asm volatile("s_waitcnt lgkmcnt(0)" ::: "memory");
    __builtin_amdgcn_sched_barrier(0);
    __builtin_amdgcn_s_setprio(1);
#pragma unroll
    for (int m = 0; m < 8; ++m)
#pragma unroll
      for (int n = 2; n < 4; ++n)
        acc[m][n] = MFMA16(a1[m], b1[n], acc[m][n]);
    __builtin_amdgcn_s_setprio(0);
    __builtin_amdgcn_sched_barrier(0);
    __builtin_amdgcn_s_barrier();
    __builtin_amdgcn_sched_barrier(0);
  }

  // Epilogue: C/D layout col = lane&15, row = (lane>>4)*4 + reg.
  const int row0 = bm * BM + wm * 128 + kg * 4;
  const int col0 = bn * BN + wn * 64 + fr;
#pragma unroll
  for (int n = 0; n < 4; ++n) {
    const int gc = col0 + n * 16;
    const float s  = scales[gc];
    const float bv = bias[gc];
#pragma unroll
    for (int m = 0; m < 8; ++m) {
      const int gr = row0 + m * 16;
#pragma unroll
      for (int r = 0; r < 4; ++r)
        C[(size_t)(gr + r) * N_TOTAL + gc] = acc[m][n][r] * s + bv;
    }
  }
#undef GLL
}

// Fallback if workspace is too small: correct but slow.
__global__ void naive_int4_kernel(const float* __restrict__ x,
                                  const int* __restrict__ wq,
                                  const float* __restrict__ scales,
                                  const float* __restrict__ bias,
                                  float* __restrict__ out) {
  size_t idx = (size_t)blockIdx.x * blockDim.x + threadIdx.x;
  int o = (int)(idx & (N_TOTAL - 1));
  int m = (int)(idx >> 12);
  const float* xr = x + (size_t)m * K_TOTAL;
  const int* wrow = wq + (size_t)o * (K_TOTAL / 2);
  float acc = 0.f;
  for (int j = 0; j < K_TOTAL / 2; ++j) {
    int b = wrow[j];
    int lo = ((b & 0xF) ^ 8) - 8;
    int hi = (((b >> 4) & 0xF) ^ 8) - 8;
    acc += xr[2 * j] * (float)lo + xr[2 * j + 1] * (float)hi;
  }
  out[idx] = acc * scales[o] + bias[o];
}

extern "C" void kernel_launch(void* const* d_in, const int* in_sizes, int n_in,
                              void* d_out, int out_size, void* d_ws, size_t ws_size,
                              hipStream_t stream) {
  const float* x      = (const float*)d_in[0];
  const int*   wq     = (const int*)d_in[1];
  const float* scales = (const float*)d_in[2];
  const float* bias   = (const float*)d_in[3];
  float* out = (float*)d_out;

  const size_t needA = (size_t)M_TOTAL * K_TOTAL * sizeof(unsigned short);  // 128 MB
  const size_t needW = (size_t)N_TOTAL * K_TOTAL * sizeof(unsigned short);  //  32 MB

  if (d_ws != nullptr && ws_size >= needA + needW) {
    unsigned short* Ab = (unsigned short*)d_ws;
    unsigned short* Wb = (unsigned short*)((char*)d_ws + needA);
    cvt_x_kernel<<<2048, 256, 0, stream>>>(x, Ab);
    dequant_w_kernel<<<1024, 256, 0, stream>>>(wq, Wb);
    gemm256_kernel<<<(M_TOTAL / BM) * (N_TOTAL / BN), 512, 0, stream>>>(Ab, Wb, scales, bias, out);
  } else {
    const size_t total = (size_t)M_TOTAL * N_TOTAL;
    naive_int4_kernel<<<(unsigned)(total / 256), 256, 0, stream>>>(x, wq, scales, bias, out);
  }
}

// Round 5
// 584.446 us; speedup vs baseline: 1.0004x; 1.0004x over previous
//
#include <hip/hip_runtime.h>
#include <hip/hip_bf16.h>
#include <stdint.h>

#define M_TOTAL 16384   // BATCH * SEQ
#define N_TOTAL 4096    // OUT_FEATURES
#define K_TOTAL 4096    // IN_FEATURES

#define BM 256
#define BN 256
#define BK 64
#define NT (K_TOTAL / BK)   // 64 K-steps

typedef __attribute__((ext_vector_type(4))) float f32x4;
typedef __attribute__((ext_vector_type(4))) int   i32x4;
typedef __attribute__((ext_vector_type(8))) short s16x8;
typedef __attribute__((ext_vector_type(4))) short s16x4;

__device__ __forceinline__ unsigned short f32_to_bf16_rne(float f) {
  union { float f; unsigned u; } c; c.f = f;
  unsigned r = (c.u + 0x7fffu + ((c.u >> 16) & 1u)) >> 16;
  return (unsigned short)r;
}

// x fp32 (M,K) -> bf16 (M,K)
__global__ void cvt_x_kernel(const float* __restrict__ x,
                             unsigned short* __restrict__ xb) {
  const int n4 = M_TOTAL * (K_TOTAL / 4);
  int idx = blockIdx.x * blockDim.x + threadIdx.x;
  int stride = gridDim.x * blockDim.x;
  const f32x4* xv = (const f32x4*)x;
  s16x4* ov = (s16x4*)xb;
  for (int i = idx; i < n4; i += stride) {
    f32x4 v = xv[i];
    s16x4 o;
#pragma unroll
    for (int j = 0; j < 4; ++j) o[j] = (short)f32_to_bf16_rne(v[j]);
    ov[i] = o;
  }
}

// packed int4 (one byte per int32 elem) -> bf16 integer values (N, K) row-major.
__global__ void dequant_w_kernel(const int* __restrict__ wq,
                                 unsigned short* __restrict__ wb) {
  const int n = (N_TOTAL * (K_TOTAL / 2)) / 4;
  int idx = blockIdx.x * blockDim.x + threadIdx.x;
  int stride = gridDim.x * blockDim.x;
  const i32x4* wv = (const i32x4*)wq;
  s16x8* ov = (s16x8*)wb;
  for (int i = idx; i < n; i += stride) {
    i32x4 w = wv[i];
    s16x8 o;
#pragma unroll
    for (int j = 0; j < 4; ++j) {
      int b = w[j];
      int lo = ((b & 0xF) ^ 8) - 8;
      int hi = (((b >> 4) & 0xF) ^ 8) - 8;
      union { float f; unsigned u; } cl, ch;
      cl.f = (float)lo; ch.f = (float)hi;
      o[2 * j]     = (short)(cl.u >> 16);
      o[2 * j + 1] = (short)(ch.u >> 16);
    }
    ov[i] = o;
  }
}

#define MFMA16(a, b, c) __builtin_amdgcn_mfma_f32_16x16x32_bf16((a), (b), (c), 0, 0, 0)

// 256x256 tile, BK=64, 8 waves (2x4). 2 barriers per K-tile; one unbarriered
// {24 ds_read + 64 MFMA} region per tile (compiler emits counted lgkm and
// interleaves kh1 reads under kh0 MFMA). Counted vmcnt gate; stage(t+2) at
// tile tail (2 tiles of latency slack). T2 LDS swizzle; T1 XCD A-ownership.
__global__ __launch_bounds__(512, 2) void gemm256_kernel(
    const unsigned short* __restrict__ A,   // M x K bf16
    const unsigned short* __restrict__ B,   // N x K bf16 (int values)
    const float* __restrict__ scales,
    const float* __restrict__ bias,
    float* __restrict__ C) {
  // [buf][A=0/B=1][256 rows][64 cols] bf16 = 128 KB total
  __shared__ unsigned short lds[2][2][BM * BK];

  const int t  = threadIdx.x;
  const int l  = t & 63;
  const int w  = t >> 6;        // wave 0..7
  const int wm = w >> 2;        // 0..1 (M half)
  const int wn = w & 3;         // 0..3 (N quarter)
  const int fr = l & 15;
  const int kg = l >> 4;        // 0..3
  const int sx = fr & 7;        // T2 swizzle XOR (row&7 == fr&7 for all frags)

  // T1/L2: each XCD (wg&7) owns an exclusive 8-tile A block, sweeps bn.
  const int wg = blockIdx.x;                        // nwg = 1024
  const int bm = (wg & 7) * 8 + ((wg >> 3) & 7);    // 0..63
  const int bn = wg >> 6;                           // 0..15

  // Staging: linear LDS dest (global_load_lds), pre-swizzled global source.
  // Thread t stores (row_in_64 = t>>3, slot = t&7); slot holds logical
  // (t&7) ^ ((t>>3)&7).
  const int rr   = t >> 3;                 // 0..63
  const int ssrc = (t & 7) ^ (rr & 7);
  const unsigned short* pa = A + (size_t)(bm * BM + rr) * K_TOTAL + ssrc * 8;
  const unsigned short* pb = B + (size_t)(bn * BN + rr) * K_TOTAL + ssrc * 8;

#define GLL(gp, lp) __builtin_amdgcn_global_load_lds( \
      (const __attribute__((address_space(1))) unsigned int*)(gp), \
      (__attribute__((address_space(3))) unsigned int*)(lp), 16, 0, 0)

  // Stage a full 64-KB tile (A + B, 8 GLL) for K-step kt into buf.
  auto stage = [&](int buf, int kt) {
#pragma unroll
    for (int g = 0; g < 4; ++g)
      GLL(pa + (size_t)g * 64 * K_TOTAL + kt, &lds[buf][0][g * 4096 + t * 8]);
#pragma unroll
    for (int g = 0; g < 4; ++g)
      GLL(pb + (size_t)g * 64 * K_TOTAL + kt, &lds[buf][1][g * 4096 + t * 8]);
  };

  f32x4 acc[8][4] = {};

  stage(0, 0);
  stage(1, BK);

  const int so0 = (kg ^ sx) * 8;         // kh0 slot (swizzled)
  const int so1 = ((4 + kg) ^ sx) * 8;   // kh1 slot

  for (int t0 = 0; t0 < NT; ++t0) {
    // Gate: tile t0's 8 GLLs (issued at tail of t0-2) landed; t0+1's in flight.
    if (t0 == NT - 1) { asm volatile("s_waitcnt vmcnt(0)" ::: "memory"); }
    else              { asm volatile("s_waitcnt vmcnt(8)" ::: "memory"); }
    __builtin_amdgcn_sched_barrier(0);
    __builtin_amdgcn_s_barrier();                       // BarA: buf[cur] ready
    __builtin_amdgcn_sched_barrier(0);

    const int cur = t0 & 1;
    const unsigned short* Abp = &lds[cur][0][(wm * 128 + fr) * BK];
    const unsigned short* Bbp = &lds[cur][1][(wn * 64 + fr) * BK];

    // Unfenced region: 24 ds_read_b128 + 64 MFMA. Compiler schedules with
    // counted lgkm; kh1 reads overlap kh0 MFMA.
    s16x8 a0[8], a1[8], b0[4], b1[4];
#pragma unroll
    for (int n = 0; n < 4; ++n) b0[n] = *(const s16x8*)&Bbp[n * 16 * BK + so0];
#pragma unroll
    for (int m = 0; m < 8; ++m) a0[m] = *(const s16x8*)&Abp[m * 16 * BK + so0];
#pragma unroll
    for (int n = 0; n < 4; ++n) b1[n] = *(const s16x8*)&Bbp[n * 16 * BK + so1];
#pragma unroll
    for (int m = 0; m < 8; ++m) a1[m] = *(const s16x8*)&Abp[m * 16 * BK + so1];

#pragma unroll
    for (int m = 0; m < 8; ++m)
#pragma unroll
      for (int n = 0; n < 4; ++n)
        acc[m][n] = MFMA16(a0[m], b0[n], acc[m][n]);
#pragma unroll
    for (int m = 0; m < 8; ++m)
#pragma unroll
      for (int n = 0; n < 4; ++n)
        acc[m][n] = MFMA16(a1[m], b1[n], acc[m][n]);

    asm volatile("s_waitcnt lgkmcnt(0)" ::: "memory");  // all reads consumed
    __builtin_amdgcn_sched_barrier(0);
    __builtin_amdgcn_s_barrier();                       // BarB: all done reading
    __builtin_amdgcn_sched_barrier(0);

    if (t0 + 2 < NT) stage(cur, (t0 + 2) * BK);         // overwrite consumed buf
  }

  // Epilogue: C/D layout col = lane&15, row = (lane>>4)*4 + reg.
  const int row0 = bm * BM + wm * 128 + kg * 4;
  const int col0 = bn * BN + wn * 64 + fr;
#pragma unroll
  for (int n = 0; n < 4; ++n) {
    const int gc = col0 + n * 16;
    const float s  = scales[gc];
    const float bv = bias[gc];
#pragma unroll
    for (int m = 0; m < 8; ++m) {
      const int gr = row0 + m * 16;
#pragma unroll
      for (int r = 0; r < 4; ++r)
        C[(size_t)(gr + r) * N_TOTAL + gc] = acc[m][n][r] * s + bv;
    }
  }
#undef GLL
}

// Fallback if workspace is too small: correct but slow.
__global__ void naive_int4_kernel(const float* __restrict__ x,
                                  const int* __restrict__ wq,
                                  const float* __restrict__ scales,
                                  const float* __restrict__ bias,
                                  float* __restrict__ out) {
  size_t idx = (size_t)blockIdx.x * blockDim.x + threadIdx.x;
  int o = (int)(idx & (N_TOTAL - 1));
  int m = (int)(idx >> 12);
  const float* xr = x + (size_t)m * K_TOTAL;
  const int* wrow = wq + (size_t)o * (K_TOTAL / 2);
  float acc = 0.f;
  for (int j = 0; j < K_TOTAL / 2; ++j) {
    int b = wrow[j];
    int lo = ((b & 0xF) ^ 8) - 8;
    int hi = (((b >> 4) & 0xF) ^ 8) - 8;
    acc += xr[2 * j] * (float)lo + xr[2 * j + 1] * (float)hi;
  }
  out[idx] = acc * scales[o] + bias[o];
}

extern "C" void kernel_launch(void* const* d_in, const int* in_sizes, int n_in,
                              void* d_out, int out_size, void* d_ws, size_t ws_size,
                              hipStream_t stream) {
  const float* x      = (const float*)d_in[0];
  const int*   wq     = (const int*)d_in[1];
  const float* scales = (const float*)d_in[2];
  const float* bias   = (const float*)d_in[3];
  float* out = (float*)d_out;

  const size_t needA = (size_t)M_TOTAL * K_TOTAL * sizeof(unsigned short);  // 128 MB
  const size_t needW = (size_t)N_TOTAL * K_TOTAL * sizeof(unsigned short);  //  32 MB

  if (d_ws != nullptr && ws_size >= needA + needW) {
    unsigned short* Ab = (unsigned short*)d_ws;
    unsigned short* Wb = (unsigned short*)((char*)d_ws + needA);
    cvt_x_kernel<<<2048, 256, 0, stream>>>(x, Ab);
    dequant_w_kernel<<<1024, 256, 0, stream>>>(wq, Wb);
    gemm256_kernel<<<(M_TOTAL / BM) * (N_TOTAL / BN), 512, 0, stream>>>(Ab, Wb, scales, bias, out);
  } else {
    const size_t total = (size_t)M_TOTAL * N_TOTAL;
    naive_int4_kernel<<<(unsigned)(total / 256), 256, 0, stream>>>(x, wq, scales, bias, out);
  }
}